// Round 1
// baseline (396.628 us; speedup 1.0000x reference)
//
#include <hip/hip_runtime.h>
#include <math.h>

#define LOG2E 1.4426950408889634f
#define LN2F  0.6931471805599453f

constexpr int M   = 2048;
constexpr int N   = 2048;
constexpr int D   = 256;
constexpr int MP1 = 2049;   // M+1 == N+1
constexpr int UVS = 2052;   // padded u/v batch stride -> float4-aligned rows
constexpr int NCHUNK = 32;
constexpr int CHUNK  = 64;  // NCHUNK*CHUNK == 2048 score rows; dustbin row added in combine

__device__ inline float fast_exp2(float x) {
#if __has_builtin(__builtin_amdgcn_exp2f)
    return __builtin_amdgcn_exp2f(x);
#else
    return exp2f(x);
#endif
}
__device__ inline float fast_log2(float x) {
#if __has_builtin(__builtin_amdgcn_logf)
    return __builtin_amdgcn_logf(x);   // v_log_f32 is log2
#else
    return log2f(x);
#endif
}
// NaN-guarded exp2 for identity (-inf) merges: fmaxf(NaN,-2e4) = -2e4 -> exp2 -> 0
__device__ inline float exp2g(float x) { return fast_exp2(fmaxf(x, -20000.0f)); }

__device__ inline void insert5(float t[5], float y) {
    float v = y, mx;
    #pragma unroll
    for (int k = 0; k < 5; ++k) { mx = fmaxf(t[k], v); v = fminf(t[k], v); t[k] = mx; }
}

// descending compare-exchange: a <- max, b <- min
__device__ inline void ce_desc(float& a, float& b) {
    float hi = fmaxf(a, b), lo = fminf(a, b); a = hi; b = lo;
}
// optimal 19-CE sorting network for 8 elements, descending (y[0] = max).
// ILP-friendly replacement for 8 serial insert5 calls.
__device__ inline void sort8_desc(float y[8]) {
    ce_desc(y[0],y[1]); ce_desc(y[2],y[3]); ce_desc(y[4],y[5]); ce_desc(y[6],y[7]);
    ce_desc(y[0],y[2]); ce_desc(y[1],y[3]); ce_desc(y[4],y[6]); ce_desc(y[5],y[7]);
    ce_desc(y[1],y[2]); ce_desc(y[5],y[6]); ce_desc(y[0],y[4]); ce_desc(y[3],y[7]);
    ce_desc(y[1],y[5]); ce_desc(y[2],y[6]);
    ce_desc(y[1],y[4]); ce_desc(y[3],y[6]);
    ce_desc(y[2],y[4]); ce_desc(y[3],y[5]);
    ce_desc(y[3],y[4]);
}

// merge sorted-desc top5 lists + lse states: merged[k]=max(a_k,b_k,max_{i+j=k-1}min(a_i,b_j))
__device__ inline void merge5(float a[5], float& as, const float b[5], float bs) {
    float r0 = fmaxf(a[0], b[0]);
    float r1 = fmaxf(fmaxf(a[1], b[1]), fminf(a[0], b[0]));
    float r2 = fmaxf(fmaxf(a[2], b[2]), fmaxf(fminf(a[1], b[0]), fminf(a[0], b[1])));
    float r3 = fmaxf(fmaxf(a[3], b[3]),
               fmaxf(fmaxf(fminf(a[2], b[0]), fminf(a[1], b[1])), fminf(a[0], b[2])));
    float r4 = fmaxf(fmaxf(a[4], b[4]),
               fmaxf(fmaxf(fminf(a[3], b[0]), fminf(a[2], b[1])),
                     fmaxf(fminf(a[1], b[2]), fminf(a[0], b[3]))));
    as = as * exp2g(a[0] - r0) + bs * exp2g(b[0] - r0);
    a[0] = r0; a[1] = r1; a[2] = r2; a[3] = r3; a[4] = r4;
}

__device__ inline void merge5_shfl_xor(float t[5], float& s, int off) {
    float b[5], bs;
    #pragma unroll
    for (int k = 0; k < 5; ++k) b[k] = __shfl_xor(t[k], off, 64);
    bs = __shfl_xor(s, off, 64);
    merge5(t, s, b, bs);
}

// online add of one element to (t,s) state; t[0] must be finite or y finite
__device__ inline void online_add(float t[5], float& s, float y) {
    float m_old = t[0];
    float m_new = fmaxf(m_old, y);
    s = s * exp2g(m_old - m_new) + fast_exp2(y - m_new);
    insert5(t, y);
}

// sort a group of 8, compute group lse-state, fold into accumulator.
// `first` is compile-time constant in unrolled callers.
__device__ inline void group_accum(bool first, float t[5], float& s, float z[8]) {
    sort8_desc(z);
    float gs = 1.0f;
    #pragma unroll
    for (int k = 1; k < 8; ++k) gs += fast_exp2(z[k] - z[0]);
    if (first) { t[0]=z[0]; t[1]=z[1]; t[2]=z[2]; t[3]=z[3]; t[4]=z[4]; s = gs; }
    else merge5(t, s, z, gs);
}

__device__ inline float gelu_exact(float x) {
    return 0.5f * x * (1.0f + erff(x * 0.70710678118654752f));
}

__device__ inline float wave_sum(float x) {
    #pragma unroll
    for (int off = 32; off >= 1; off >>= 1) x += __shfl_xor(x, off, 64);
    return x;
}

// one-wave MLP: 16 -> 64 gelu LN -> 64 gelu LN -> 1. f[] is lane-uniform, j = lane.
// returns wave-uniform scalar output.
__device__ inline float mlp_wave(const float f[16], int j,
    const float* __restrict__ w1, const float* __restrict__ b1,
    const float* __restrict__ g1, const float* __restrict__ be1,
    const float* __restrict__ w2, const float* __restrict__ b2,
    const float* __restrict__ g2, const float* __restrict__ be2,
    const float* __restrict__ w3, const float* __restrict__ b3)
{
    float h = b1[j];
    #pragma unroll
    for (int k = 0; k < 16; ++k) h = fmaf(f[k], w1[j * 16 + k], h);
    h = gelu_exact(h);
    float mu  = wave_sum(h) * (1.0f / 64.0f);
    float d   = h - mu;
    float var = wave_sum(d * d) * (1.0f / 64.0f);
    float hn  = d * rsqrtf(var + 1e-5f) * g1[j] + be1[j];
    float h2 = b2[j];
    #pragma unroll
    for (int k = 0; k < 64; ++k) h2 = fmaf(__shfl(hn, k, 64), w2[j * 64 + k], h2);
    h2 = gelu_exact(h2);
    mu  = wave_sum(h2) * (1.0f / 64.0f);
    d   = h2 - mu;
    var = wave_sum(d * d) * (1.0f / 64.0f);
    float hn2 = d * rsqrtf(var + 1e-5f) * g2[j] + be2[j];
    return wave_sum(hn2 * w3[j]) + b3[0];
}

// ---------------------------------------------------------------------------
// dA[b,m,p] = sum_d mdesc[b,d,m] * pw[p,d] + pb[p];  dustbin row m==M -> 0
// grid (9, B, 2), block 256
// ---------------------------------------------------------------------------
__global__ __launch_bounds__(256) void proj_kernel(
    const float* __restrict__ mdesc0, const float* __restrict__ mdesc1,
    const float* __restrict__ pA_w, const float* __restrict__ pA_b,
    const float* __restrict__ pB_w, const float* __restrict__ pB_b,
    float* __restrict__ dA, float* __restrict__ dB)
{
    const int which = blockIdx.z;
    const float* mdesc = which ? mdesc1 : mdesc0;
    const float* pw    = which ? pB_w : pA_w;
    const float* pb    = which ? pB_b : pA_b;
    float* dOut        = which ? dB   : dA;

    __shared__ float swT[D * 8];   // transposed: swT[d*8+p]
    const int tid = threadIdx.x;
    for (int idx = tid; idx < 8 * D; idx += 256) {
        int p = idx >> 8, d = idx & (D - 1);
        swT[d * 8 + p] = pw[idx];
    }
    __syncthreads();

    const int m = blockIdx.x * 256 + tid;
    const int b = blockIdx.y;
    if (m > M) return;
    float* out = dOut + ((size_t)b * MP1 + m) * 8;
    if (m == M) {
        #pragma unroll
        for (int p = 0; p < 8; ++p) out[p] = 0.0f;
        return;
    }
    float acc[8];
    #pragma unroll
    for (int p = 0; p < 8; ++p) acc[p] = pb[p];
    const float* base = mdesc + (size_t)b * D * M + m;
    #pragma unroll 4
    for (int d = 0; d < D; ++d) {
        float x = base[(size_t)d * M];
        #pragma unroll
        for (int p = 0; p < 8; ++p) acc[p] = fmaf(x, swT[d * 8 + p], acc[p]);
    }
    #pragma unroll
    for (int p = 0; p < 8; ++p) out[p] = acc[p];
}

// ---------------------------------------------------------------------------
// Row pass + fused MLP. grid (513, B), block 256 = 4 independent waves,
// one row per wave (no LDS, no barriers, no idle-wave exit).
// Each wave: 8 float4 loads (32 elems/lane), 4 sort8 groups, 3 serial merges,
// 6-level butterfly, dustbin add, feats, MLP, write u.
// ---------------------------------------------------------------------------
__global__ __launch_bounds__(256) void row_fused(
    const float* __restrict__ scores, const float* __restrict__ alpha,
    const float* __restrict__ v, const float* __restrict__ dA,
    float* __restrict__ u, int first_iter,
    const float* __restrict__ w1, const float* __restrict__ b1,
    const float* __restrict__ g1, const float* __restrict__ be1,
    const float* __restrict__ w2, const float* __restrict__ b2,
    const float* __restrict__ g2, const float* __restrict__ be2,
    const float* __restrict__ w3, const float* __restrict__ b3)
{
    const int tid  = threadIdx.x;
    const int lane = tid & 63;
    const int wv   = tid >> 6;
    const int r    = blockIdx.x * 4 + wv;
    const int b    = blockIdx.y;
    if (r >= MP1) return;

    const float alpha2 = alpha[0] * LOG2E;
    const float* vb = v + (size_t)b * UVS;
    const float4* v4 = (const float4*)vb;

    float t[5]; float s;
    if (r < M) {
        const float4* s4 = (const float4*)(scores + ((size_t)b * M + r) * N);
        #pragma unroll
        for (int g = 0; g < 4; ++g) {
            float4 qa = s4[lane + 128 * g];
            float4 qb = s4[lane + 128 * g + 64];
            float z[8];
            if (first_iter) {
                z[0]=qa.x*LOG2E; z[1]=qa.y*LOG2E; z[2]=qa.z*LOG2E; z[3]=qa.w*LOG2E;
                z[4]=qb.x*LOG2E; z[5]=qb.y*LOG2E; z[6]=qb.z*LOG2E; z[7]=qb.w*LOG2E;
            } else {
                float4 wa = v4[lane + 128 * g];
                float4 wb = v4[lane + 128 * g + 64];
                z[0]=fmaf(qa.x,LOG2E,wa.x); z[1]=fmaf(qa.y,LOG2E,wa.y);
                z[2]=fmaf(qa.z,LOG2E,wa.z); z[3]=fmaf(qa.w,LOG2E,wa.w);
                z[4]=fmaf(qb.x,LOG2E,wb.x); z[5]=fmaf(qb.y,LOG2E,wb.y);
                z[6]=fmaf(qb.z,LOG2E,wb.z); z[7]=fmaf(qb.w,LOG2E,wb.w);
            }
            group_accum(g == 0, t, s, z);
        }
    } else {   // dustbin row: value alpha2 (+ v[c])
        #pragma unroll
        for (int g = 0; g < 4; ++g) {
            float z[8];
            if (first_iter) {
                #pragma unroll
                for (int k = 0; k < 8; ++k) z[k] = alpha2;
            } else {
                float4 wa = v4[lane + 128 * g];
                float4 wb = v4[lane + 128 * g + 64];
                z[0]=alpha2+wa.x; z[1]=alpha2+wa.y; z[2]=alpha2+wa.z; z[3]=alpha2+wa.w;
                z[4]=alpha2+wb.x; z[5]=alpha2+wb.y; z[6]=alpha2+wb.z; z[7]=alpha2+wb.w;
            }
            group_accum(g == 0, t, s, z);
        }
    }

    // wave butterfly merge -> full-row state replicated on all 64 lanes
    #pragma unroll
    for (int off = 32; off >= 1; off >>= 1) merge5_shfl_xor(t, s, off);

    // dustbin column element (identical on all lanes -> replicated add, no divergence)
    float extra = first_iter ? alpha2 : (alpha2 + vb[N]);
    online_add(t, s, extra);

    float lse = t[0] + fast_log2(s);
    float l2w = (r < M) ? -12.0f : -1.0f;   // norm=-log2(4096); log2(N)+norm
    float un  = l2w - lse;
    const int i = b * MP1 + r;

    float f[16];
    f[0] = l2w * LN2F;
    f[1] = un  * LN2F;
    f[2] = 0.0f;
    f[3] = (t[0] - t[1]) * LN2F;
    f[4] = (t[0] - t[2]) * LN2F;
    f[5] = (t[0] - t[3]) * LN2F;
    f[6] = (t[0] - t[4]) * LN2F;
    f[7] = (lse - t[0]) * LN2F;
    const float* dd = dA + (size_t)i * 8;
    #pragma unroll
    for (int p = 0; p < 8; ++p) f[8 + p] = dd[p];

    float o = mlp_wave(f, lane, w1, b1, g1, be1, w2, b2, g2, be2, w3, b3);
    if (lane == 0) u[(size_t)b * UVS + r] = un + o * LOG2E;
}

// ---------------------------------------------------------------------------
// Col pass: grid (9, NCHUNK, B), block 256. Thread owns column c, reduces its
// CHUNK=64 rows as 8 sort8-groups + merge tree (short dep chains). u is read
// at wave-uniform addresses (scalar loads) - no LDS, no barrier.
// partial layout: [b][chunk][c][8]  (write-coalesced, float4-aligned)
// ---------------------------------------------------------------------------
__global__ __launch_bounds__(256) void col_pass(
    const float* __restrict__ scores, const float* __restrict__ alpha,
    const float* __restrict__ u, float* __restrict__ partial)
{
    const int tid = threadIdx.x;
    const int chunk = blockIdx.y;
    const int b = blockIdx.z;
    const int r0 = chunk * CHUNK;
    const int c = blockIdx.x * 256 + tid;
    if (c > N) return;

    const float alpha2 = alpha[0] * LOG2E;
    const float* __restrict__ ub = u + (size_t)b * UVS + r0;

    float t[5]; float s;
    if (c < N) {
        const float* base = scores + (size_t)b * M * N + (size_t)r0 * N + c;
        #pragma unroll
        for (int g = 0; g < 8; ++g) {
            float z[8];
            #pragma unroll
            for (int k = 0; k < 8; ++k)
                z[k] = fmaf(base[(size_t)(8 * g + k) * N], LOG2E, ub[8 * g + k]);
            group_accum(g == 0, t, s, z);
        }
    } else {   // dustbin column: alpha2 + u[r]
        #pragma unroll
        for (int g = 0; g < 8; ++g) {
            float z[8];
            #pragma unroll
            for (int k = 0; k < 8; ++k) z[k] = alpha2 + ub[8 * g + k];
            group_accum(g == 0, t, s, z);
        }
    }

    float4* p4 = (float4*)(partial + (((size_t)(b * NCHUNK + chunk) * MP1) + c) * 8);
    p4[0] = make_float4(t[0], t[1], t[2], t[3]);
    p4[1] = make_float4(t[4], s, 0.0f, 0.0f);
}

// ---------------------------------------------------------------------------
// Col combine + fused MLP: grid (513, B), block 256 = 4 independent waves,
// one column per wave. lane k<NCHUNK loads partial k; butterfly merge
// (NaN-guarded for identity lanes); add dustbin row; feats; MLP; write v.
// ---------------------------------------------------------------------------
__global__ __launch_bounds__(256) void col_mlp_fused(
    const float* __restrict__ partial, const float* __restrict__ dB,
    const float* __restrict__ u, const float* __restrict__ alpha,
    float* __restrict__ v,
    const float* __restrict__ w1, const float* __restrict__ b1,
    const float* __restrict__ g1, const float* __restrict__ be1,
    const float* __restrict__ w2, const float* __restrict__ b2,
    const float* __restrict__ g2, const float* __restrict__ be2,
    const float* __restrict__ w3, const float* __restrict__ b3)
{
    const int tid  = threadIdx.x;
    const int lane = tid & 63;
    const int wv   = tid >> 6;
    const int c = blockIdx.x * 4 + wv;
    const int b = blockIdx.y;
    if (c >= MP1) return;
    const float alpha2 = alpha[0] * LOG2E;

    float t[5], s;
    if (lane < NCHUNK) {
        const float4* p4 = (const float4*)(partial + (((size_t)(b * NCHUNK + lane) * MP1) + c) * 8);
        float4 A = p4[0], Bv = p4[1];
        t[0] = A.x; t[1] = A.y; t[2] = A.z; t[3] = A.w; t[4] = Bv.x; s = Bv.y;
    } else {
        #pragma unroll
        for (int k = 0; k < 5; ++k) t[k] = -INFINITY;
        s = 0.0f;
    }
    #pragma unroll
    for (int off = 32; off >= 1; off >>= 1) merge5_shfl_xor(t, s, off);

    // dustbin row r==M: value alpha2 + u[M] for every column (incl. c==N)
    online_add(t, s, alpha2 + u[(size_t)b * UVS + M]);

    float lse = t[0] + fast_log2(s);
    float l2w = (c < N) ? -12.0f : -1.0f;
    float vn  = l2w - lse;
    const int i = b * MP1 + c;

    float f[16];
    f[0] = l2w * LN2F;
    f[1] = vn  * LN2F;
    f[2] = 0.0f;
    f[3] = (t[0] - t[1]) * LN2F;
    f[4] = (t[0] - t[2]) * LN2F;
    f[5] = (t[0] - t[3]) * LN2F;
    f[6] = (t[0] - t[4]) * LN2F;
    f[7] = (lse - t[0]) * LN2F;
    const float* dd = dB + (size_t)i * 8;
    #pragma unroll
    for (int p = 0; p < 8; ++p) f[8 + p] = dd[p];

    float o = mlp_wave(f, lane, w1, b1, g1, be1, w2, b2, g2, be2, w3, b3);
    if (lane == 0) v[(size_t)b * UVS + c] = vn + o * LOG2E;
}

// ---------------------------------------------------------------------------
// out[b,r,c] = S*LOG2E + u[b,r] + v[b,c] + 12.  grid (2049, B), block 256.
// ---------------------------------------------------------------------------
__global__ __launch_bounds__(256) void final_kernel(
    const float* __restrict__ scores, const float* __restrict__ alpha,
    const float* __restrict__ u, const float* __restrict__ v,
    float* __restrict__ out)
{
    const int r = blockIdx.x;
    const int b = blockIdx.y;
    const int tid = threadIdx.x;
    const float alpha2 = alpha[0] * LOG2E;
    const float* vb = v + (size_t)b * UVS;
    const float ur = u[(size_t)b * UVS + r] + 12.0f;
    float* orow = out + ((size_t)b * MP1 + r) * MP1;

    if (r < M) {
        const float* srow = scores + ((size_t)b * M + r) * N;
        #pragma unroll
        for (int k = 0; k < 8; ++k) {
            int c = tid + 256 * k;
            orow[c] = fmaf(srow[c], LOG2E, ur + vb[c]);
        }
    } else {
        #pragma unroll
        for (int k = 0; k < 8; ++k) {
            int c = tid + 256 * k;
            orow[c] = alpha2 + ur + vb[c];
        }
    }
    if (tid == 0) orow[N] = alpha2 + ur + vb[N];
}

extern "C" void kernel_launch(void* const* d_in, const int* in_sizes, int n_in,
                              void* d_out, int out_size, void* d_ws, size_t ws_size,
                              hipStream_t stream) {
    const float* scores = (const float*)d_in[0];
    const float* alpha  = (const float*)d_in[1];
    const float* mdesc0 = (const float*)d_in[2];
    const float* mdesc1 = (const float*)d_in[3];
    const float* pA_w = (const float*)d_in[4];
    const float* pA_b = (const float*)d_in[5];
    const float* pB_w = (const float*)d_in[6];
    const float* pB_b = (const float*)d_in[7];
    const float* rW[10]; const float* cW[10];
    for (int k = 0; k < 10; ++k) rW[k] = (const float*)d_in[8 + k];
    for (int k = 0; k < 10; ++k) cW[k] = (const float*)d_in[18 + k];
    float* out = (float*)d_out;

    const int B = in_sizes[0] / (M * N);

    float* ws = (float*)d_ws;
    float* u       = ws;                        // B*UVS
    float* v       = u + (size_t)B * UVS;       // B*UVS
    float* dA      = v + (size_t)B * UVS;       // B*MP1*8
    float* dB      = dA + (size_t)B * MP1 * 8;  // B*MP1*8
    float* partial = dB + (size_t)B * MP1 * 8;  // B*NCHUNK*MP1*8

    const int CB = (MP1 + 255) / 256; // 9
    const int RB = (MP1 + 3) / 4;     // 513: 4 rows/cols per block, 1 per wave

    proj_kernel<<<dim3(CB, B, 2), 256, 0, stream>>>(
        mdesc0, mdesc1, pA_w, pA_b, pB_w, pB_b, dA, dB);

    for (int it = 0; it < 3; ++it) {
        row_fused<<<dim3(RB, B), 256, 0, stream>>>(
            scores, alpha, v, dA, u, it == 0 ? 1 : 0,
            rW[0], rW[1], rW[2], rW[3], rW[4], rW[5], rW[6], rW[7], rW[8], rW[9]);
        col_pass<<<dim3(CB, NCHUNK, B), 256, 0, stream>>>(scores, alpha, u, partial);
        col_mlp_fused<<<dim3(RB, B), 256, 0, stream>>>(
            partial, dB, u, alpha, v,
            cW[0], cW[1], cW[2], cW[3], cW[4], cW[5], cW[6], cW[7], cW[8], cW[9]);
    }
    final_kernel<<<dim3(MP1, B), 256, 0, stream>>>(scores, alpha, u, v, out);
}

// Round 2
// 387.435 us; speedup vs baseline: 1.0237x; 1.0237x over previous
//
#include <hip/hip_runtime.h>
#include <math.h>

#define LOG2E 1.4426950408889634f
#define LN2F  0.6931471805599453f

constexpr int M   = 2048;
constexpr int N   = 2048;
constexpr int D   = 256;
constexpr int MP1 = 2049;   // M+1 == N+1
constexpr int UVS = 2052;   // padded u/v batch stride -> float4-aligned rows
constexpr int NCHUNK = 32;
constexpr int CHUNK  = 64;  // NCHUNK*CHUNK == 2048 score rows; dustbin row added in combine

__device__ inline float fast_exp2(float x) {
#if __has_builtin(__builtin_amdgcn_exp2f)
    return __builtin_amdgcn_exp2f(x);
#else
    return exp2f(x);
#endif
}
__device__ inline float fast_log2(float x) {
#if __has_builtin(__builtin_amdgcn_logf)
    return __builtin_amdgcn_logf(x);   // v_log_f32 is log2
#else
    return log2f(x);
#endif
}
// NaN-guarded exp2 for identity (-inf) merges: fmaxf(NaN,-2e4) = -2e4 -> exp2 -> 0
__device__ inline float exp2g(float x) { return fast_exp2(fmaxf(x, -20000.0f)); }

__device__ inline void insert5(float t[5], float y) {
    float v = y, mx;
    #pragma unroll
    for (int k = 0; k < 5; ++k) { mx = fmaxf(t[k], v); v = fminf(t[k], v); t[k] = mx; }
}

// descending compare-exchange: a <- max, b <- min
__device__ inline void ce_desc(float& a, float& b) {
    float hi = fmaxf(a, b), lo = fminf(a, b); a = hi; b = lo;
}
// 19-CE sorting network for 8 elements, descending (y[0] = max). ILP-friendly.
__device__ inline void sort8_desc(float y[8]) {
    ce_desc(y[0],y[1]); ce_desc(y[2],y[3]); ce_desc(y[4],y[5]); ce_desc(y[6],y[7]);
    ce_desc(y[0],y[2]); ce_desc(y[1],y[3]); ce_desc(y[4],y[6]); ce_desc(y[5],y[7]);
    ce_desc(y[1],y[2]); ce_desc(y[5],y[6]); ce_desc(y[0],y[4]); ce_desc(y[3],y[7]);
    ce_desc(y[1],y[5]); ce_desc(y[2],y[6]);
    ce_desc(y[1],y[4]); ce_desc(y[3],y[6]);
    ce_desc(y[2],y[4]); ce_desc(y[3],y[5]);
    ce_desc(y[3],y[4]);
}

// merge sorted-desc top5 lists + lse states
__device__ inline void merge5(float a[5], float& as, const float b[5], float bs) {
    float r0 = fmaxf(a[0], b[0]);
    float r1 = fmaxf(fmaxf(a[1], b[1]), fminf(a[0], b[0]));
    float r2 = fmaxf(fmaxf(a[2], b[2]), fmaxf(fminf(a[1], b[0]), fminf(a[0], b[1])));
    float r3 = fmaxf(fmaxf(a[3], b[3]),
               fmaxf(fmaxf(fminf(a[2], b[0]), fminf(a[1], b[1])), fminf(a[0], b[2])));
    float r4 = fmaxf(fmaxf(a[4], b[4]),
               fmaxf(fmaxf(fminf(a[3], b[0]), fminf(a[2], b[1])),
                     fmaxf(fminf(a[1], b[2]), fminf(a[0], b[3]))));
    as = as * exp2g(a[0] - r0) + bs * exp2g(b[0] - r0);
    a[0] = r0; a[1] = r1; a[2] = r2; a[3] = r3; a[4] = r4;
}

__device__ inline void merge5_shfl_xor(float t[5], float& s, int off) {
    float b[5], bs;
    #pragma unroll
    for (int k = 0; k < 5; ++k) b[k] = __shfl_xor(t[k], off, 64);
    bs = __shfl_xor(s, off, 64);
    merge5(t, s, b, bs);
}

// dual butterfly level: two independent states interleaved (ILP + shfl latency hiding)
__device__ inline void merge5_shfl_xor2(float tA[5], float& sA, float tB[5], float& sB, int off) {
    float bA[5], bB[5];
    #pragma unroll
    for (int k = 0; k < 5; ++k) { bA[k] = __shfl_xor(tA[k], off, 64); bB[k] = __shfl_xor(tB[k], off, 64); }
    float bsA = __shfl_xor(sA, off, 64);
    float bsB = __shfl_xor(sB, off, 64);
    merge5(tA, sA, bA, bsA);
    merge5(tB, sB, bB, bsB);
}

// online add of one element to (t,s) state
__device__ inline void online_add(float t[5], float& s, float y) {
    float m_old = t[0];
    float m_new = fmaxf(m_old, y);
    s = s * exp2g(m_old - m_new) + fast_exp2(y - m_new);
    insert5(t, y);
}

// sort a group of 8, compute group lse-state, fold into accumulator.
__device__ inline void group_accum(bool first, float t[5], float& s, float z[8]) {
    sort8_desc(z);
    float gs = 1.0f;
    #pragma unroll
    for (int k = 1; k < 8; ++k) gs += fast_exp2(z[k] - z[0]);
    if (first) { t[0]=z[0]; t[1]=z[1]; t[2]=z[2]; t[3]=z[3]; t[4]=z[4]; s = gs; }
    else merge5(t, s, z, gs);
}

__device__ inline float gelu_exact(float x) {
    return 0.5f * x * (1.0f + erff(x * 0.70710678118654752f));
}

__device__ inline float wave_sum(float x) {
    #pragma unroll
    for (int off = 32; off >= 1; off >>= 1) x += __shfl_xor(x, off, 64);
    return x;
}
__device__ inline void wave_sum2(float& x, float& y) {
    #pragma unroll
    for (int off = 32; off >= 1; off >>= 1) {
        float xs = __shfl_xor(x, off, 64);
        float ys = __shfl_xor(y, off, 64);
        x += xs; y += ys;
    }
}

// one-wave MLP: 16 -> 64 gelu LN -> 64 gelu LN -> 1. f[] lane-uniform, j = lane.
__device__ inline float mlp_wave(const float f[16], int j,
    const float* __restrict__ w1, const float* __restrict__ b1,
    const float* __restrict__ g1, const float* __restrict__ be1,
    const float* __restrict__ w2, const float* __restrict__ b2,
    const float* __restrict__ g2, const float* __restrict__ be2,
    const float* __restrict__ w3, const float* __restrict__ b3)
{
    float h = b1[j];
    #pragma unroll
    for (int k = 0; k < 16; ++k) h = fmaf(f[k], w1[j * 16 + k], h);
    h = gelu_exact(h);
    float mu  = wave_sum(h) * (1.0f / 64.0f);
    float d   = h - mu;
    float var = wave_sum(d * d) * (1.0f / 64.0f);
    float hn  = d * rsqrtf(var + 1e-5f) * g1[j] + be1[j];
    float h2 = b2[j];
    #pragma unroll
    for (int k = 0; k < 64; ++k) h2 = fmaf(__shfl(hn, k, 64), w2[j * 64 + k], h2);
    h2 = gelu_exact(h2);
    mu  = wave_sum(h2) * (1.0f / 64.0f);
    d   = h2 - mu;
    var = wave_sum(d * d) * (1.0f / 64.0f);
    float hn2 = d * rsqrtf(var + 1e-5f) * g2[j] + be2[j];
    return wave_sum(hn2 * w3[j]) + b3[0];
}

// dual MLP: two independent rows through the same weights (shared weight loads,
// 2-way ILP in every serial section, split accumulators in layer 2)
__device__ inline void mlp_wave2(const float fA[16], const float fB[16], int j,
    const float* __restrict__ w1, const float* __restrict__ b1,
    const float* __restrict__ g1, const float* __restrict__ be1,
    const float* __restrict__ w2, const float* __restrict__ b2,
    const float* __restrict__ g2, const float* __restrict__ be2,
    const float* __restrict__ w3, const float* __restrict__ b3,
    float& oA, float& oB)
{
    float hA = b1[j], hB = hA;
    #pragma unroll
    for (int k = 0; k < 16; ++k) {
        float w = w1[j * 16 + k];
        hA = fmaf(fA[k], w, hA);
        hB = fmaf(fB[k], w, hB);
    }
    hA = gelu_exact(hA); hB = gelu_exact(hB);
    float muA = hA, muB = hB;
    wave_sum2(muA, muB);
    muA *= (1.0f / 64.0f); muB *= (1.0f / 64.0f);
    float dA = hA - muA, dB = hB - muB;
    float vA = dA * dA, vB = dB * dB;
    wave_sum2(vA, vB);
    vA *= (1.0f / 64.0f); vB *= (1.0f / 64.0f);
    float hnA = dA * rsqrtf(vA + 1e-5f) * g1[j] + be1[j];
    float hnB = dB * rsqrtf(vB + 1e-5f) * g1[j] + be1[j];

    float a0A = b2[j], a1A = 0.0f, a0B = b2[j], a1B = 0.0f;
    #pragma unroll
    for (int k = 0; k < 64; k += 2) {
        float w0 = w2[j * 64 + k], w1v = w2[j * 64 + k + 1];
        float sA0 = __shfl(hnA, k, 64),     sB0 = __shfl(hnB, k, 64);
        float sA1 = __shfl(hnA, k + 1, 64), sB1 = __shfl(hnB, k + 1, 64);
        a0A = fmaf(sA0, w0, a0A); a0B = fmaf(sB0, w0, a0B);
        a1A = fmaf(sA1, w1v, a1A); a1B = fmaf(sB1, w1v, a1B);
    }
    float h2A = gelu_exact(a0A + a1A), h2B = gelu_exact(a0B + a1B);
    muA = h2A; muB = h2B;
    wave_sum2(muA, muB);
    muA *= (1.0f / 64.0f); muB *= (1.0f / 64.0f);
    dA = h2A - muA; dB = h2B - muB;
    vA = dA * dA; vB = dB * dB;
    wave_sum2(vA, vB);
    vA *= (1.0f / 64.0f); vB *= (1.0f / 64.0f);
    float hn2A = dA * rsqrtf(vA + 1e-5f) * g2[j] + be2[j];
    float hn2B = dB * rsqrtf(vB + 1e-5f) * g2[j] + be2[j];
    float zA = hn2A * w3[j], zB = hn2B * w3[j];
    wave_sum2(zA, zB);
    oA = zA + b3[0];
    oB = zB + b3[0];
}

__device__ inline void feats_from(float t[5], float s, float l2w, float nrm,
                                  const float* __restrict__ dd, float f[16], float& un)
{
    float lse = t[0] + fast_log2(s);
    un = l2w - lse;
    f[0] = l2w * LN2F;
    f[1] = un  * LN2F;
    f[2] = 0.0f;
    f[3] = (t[0] - t[1]) * LN2F;
    f[4] = (t[0] - t[2]) * LN2F;
    f[5] = (t[0] - t[3]) * LN2F;
    f[6] = (t[0] - t[4]) * LN2F;
    f[7] = (lse - t[0]) * LN2F;
    (void)nrm;
    #pragma unroll
    for (int p = 0; p < 8; ++p) f[8 + p] = dd[p];
}

// ---------------------------------------------------------------------------
// dA[b,m,p] = sum_d mdesc[b,d,m] * pw[p,d] + pb[p];  dustbin row m==M -> 0
// grid (9, B, 2), block 256
// ---------------------------------------------------------------------------
__global__ __launch_bounds__(256) void proj_kernel(
    const float* __restrict__ mdesc0, const float* __restrict__ mdesc1,
    const float* __restrict__ pA_w, const float* __restrict__ pA_b,
    const float* __restrict__ pB_w, const float* __restrict__ pB_b,
    float* __restrict__ dA, float* __restrict__ dB)
{
    const int which = blockIdx.z;
    const float* mdesc = which ? mdesc1 : mdesc0;
    const float* pw    = which ? pB_w : pA_w;
    const float* pb    = which ? pB_b : pA_b;
    float* dOut        = which ? dB   : dA;

    __shared__ float swT[D * 8];   // transposed: swT[d*8+p]
    const int tid = threadIdx.x;
    for (int idx = tid; idx < 8 * D; idx += 256) {
        int p = idx >> 8, d = idx & (D - 1);
        swT[d * 8 + p] = pw[idx];
    }
    __syncthreads();

    const int m = blockIdx.x * 256 + tid;
    const int b = blockIdx.y;
    if (m > M) return;
    float* out = dOut + ((size_t)b * MP1 + m) * 8;
    if (m == M) {
        #pragma unroll
        for (int p = 0; p < 8; ++p) out[p] = 0.0f;
        return;
    }
    float acc[8];
    #pragma unroll
    for (int p = 0; p < 8; ++p) acc[p] = pb[p];
    const float* base = mdesc + (size_t)b * D * M + m;
    #pragma unroll 4
    for (int d = 0; d < D; ++d) {
        float x = base[(size_t)d * M];
        #pragma unroll
        for (int p = 0; p < 8; ++p) acc[p] = fmaf(x, swT[d * 8 + p], acc[p]);
    }
    #pragma unroll
    for (int p = 0; p < 8; ++p) out[p] = acc[p];
}

// ---------------------------------------------------------------------------
// Row pass + fused MLP. grid (257, B), block 256 = 4 waves, TWO rows per wave.
// All loads (v shared + both rows' scores) issue before any reduce -> loads of
// row B are in flight under row A's compute. Dual butterfly + dual MLP.
// ---------------------------------------------------------------------------
__global__ __launch_bounds__(256) void row_fused(
    const float* __restrict__ scores, const float* __restrict__ alpha,
    const float* __restrict__ v, const float* __restrict__ dA,
    float* __restrict__ u, int first_iter,
    const float* __restrict__ w1, const float* __restrict__ b1,
    const float* __restrict__ g1, const float* __restrict__ be1,
    const float* __restrict__ w2, const float* __restrict__ b2,
    const float* __restrict__ g2, const float* __restrict__ be2,
    const float* __restrict__ w3, const float* __restrict__ b3)
{
    const int tid  = threadIdx.x;
    const int lane = tid & 63;
    const int wv   = tid >> 6;
    const int pair = blockIdx.x * 4 + wv;
    const int r0   = pair * 2;
    if (r0 >= MP1) return;
    const int b = blockIdx.y;

    const float alpha2 = alpha[0] * LOG2E;
    const float* vb = v + (size_t)b * UVS;
    const float4* v4 = (const float4*)vb;

    if (r0 < M) {
        // ---- dual path: rows r0, r0+1 both normal ----
        const float4* sA4 = (const float4*)(scores + ((size_t)b * M + r0) * N);
        const float4* sB4 = sA4 + (N / 4);

        float4 vv[8], qA[8], qB[8];
        if (!first_iter) {
            #pragma unroll
            for (int j = 0; j < 8; ++j) vv[j] = v4[lane + 64 * j];
        }
        #pragma unroll
        for (int j = 0; j < 8; ++j) qA[j] = sA4[lane + 64 * j];
        #pragma unroll
        for (int j = 0; j < 8; ++j) qB[j] = sB4[lane + 64 * j];

        float tA[5], sA, tB[5], sB;
        #pragma unroll
        for (int g = 0; g < 4; ++g) {
            float z[8];
            float4 qa = qA[2 * g], qb = qA[2 * g + 1];
            if (first_iter) {
                z[0]=qa.x*LOG2E; z[1]=qa.y*LOG2E; z[2]=qa.z*LOG2E; z[3]=qa.w*LOG2E;
                z[4]=qb.x*LOG2E; z[5]=qb.y*LOG2E; z[6]=qb.z*LOG2E; z[7]=qb.w*LOG2E;
            } else {
                float4 wa = vv[2 * g], wb = vv[2 * g + 1];
                z[0]=fmaf(qa.x,LOG2E,wa.x); z[1]=fmaf(qa.y,LOG2E,wa.y);
                z[2]=fmaf(qa.z,LOG2E,wa.z); z[3]=fmaf(qa.w,LOG2E,wa.w);
                z[4]=fmaf(qb.x,LOG2E,wb.x); z[5]=fmaf(qb.y,LOG2E,wb.y);
                z[6]=fmaf(qb.z,LOG2E,wb.z); z[7]=fmaf(qb.w,LOG2E,wb.w);
            }
            group_accum(g == 0, tA, sA, z);
        }
        #pragma unroll
        for (int g = 0; g < 4; ++g) {
            float z[8];
            float4 qa = qB[2 * g], qb = qB[2 * g + 1];
            if (first_iter) {
                z[0]=qa.x*LOG2E; z[1]=qa.y*LOG2E; z[2]=qa.z*LOG2E; z[3]=qa.w*LOG2E;
                z[4]=qb.x*LOG2E; z[5]=qb.y*LOG2E; z[6]=qb.z*LOG2E; z[7]=qb.w*LOG2E;
            } else {
                float4 wa = vv[2 * g], wb = vv[2 * g + 1];
                z[0]=fmaf(qa.x,LOG2E,wa.x); z[1]=fmaf(qa.y,LOG2E,wa.y);
                z[2]=fmaf(qa.z,LOG2E,wa.z); z[3]=fmaf(qa.w,LOG2E,wa.w);
                z[4]=fmaf(qb.x,LOG2E,wb.x); z[5]=fmaf(qb.y,LOG2E,wb.y);
                z[6]=fmaf(qb.z,LOG2E,wb.z); z[7]=fmaf(qb.w,LOG2E,wb.w);
            }
            group_accum(g == 0, tB, sB, z);
        }

        #pragma unroll
        for (int off = 32; off >= 1; off >>= 1) merge5_shfl_xor2(tA, sA, tB, sB, off);

        float extra = first_iter ? alpha2 : (alpha2 + vb[N]);
        online_add(tA, sA, extra);
        online_add(tB, sB, extra);

        float fA[16], fB[16], unA, unB;
        const float* ddA = dA + (size_t)(b * MP1 + r0) * 8;
        const float* ddB = ddA + 8;
        feats_from(tA, sA, -12.0f, 0.0f, ddA, fA, unA);
        feats_from(tB, sB, -12.0f, 0.0f, ddB, fB, unB);

        float oA, oB;
        mlp_wave2(fA, fB, lane, w1, b1, g1, be1, w2, b2, g2, be2, w3, b3, oA, oB);
        if (lane == 0) {
            u[(size_t)b * UVS + r0]     = unA + oA * LOG2E;
            u[(size_t)b * UVS + r0 + 1] = unB + oB * LOG2E;
        }
    } else {
        // ---- single path: dustbin row r0 == M ----
        float t[5], s;
        #pragma unroll
        for (int g = 0; g < 4; ++g) {
            float z[8];
            if (first_iter) {
                #pragma unroll
                for (int k = 0; k < 8; ++k) z[k] = alpha2;
            } else {
                float4 wa = v4[lane + 128 * g];
                float4 wb = v4[lane + 128 * g + 64];
                z[0]=alpha2+wa.x; z[1]=alpha2+wa.y; z[2]=alpha2+wa.z; z[3]=alpha2+wa.w;
                z[4]=alpha2+wb.x; z[5]=alpha2+wb.y; z[6]=alpha2+wb.z; z[7]=alpha2+wb.w;
            }
            group_accum(g == 0, t, s, z);
        }
        #pragma unroll
        for (int off = 32; off >= 1; off >>= 1) merge5_shfl_xor(t, s, off);
        float extra = first_iter ? alpha2 : (alpha2 + vb[N]);
        online_add(t, s, extra);

        float f[16], un;
        const float* dd = dA + (size_t)(b * MP1 + M) * 8;
        feats_from(t, s, -1.0f, 0.0f, dd, f, un);
        float o = mlp_wave(f, lane, w1, b1, g1, be1, w2, b2, g2, be2, w3, b3);
        if (lane == 0) u[(size_t)b * UVS + M] = un + o * LOG2E;
    }
}

// ---------------------------------------------------------------------------
// Col pass: grid (4, NCHUNK, B), block 256. Thread owns TWO columns (float2
// loads), reduces CHUNK=64 rows as 8 sort8-groups per column. Dustbin column
// handled entirely in col_mlp_fused. u reads are wave-uniform (s_loads).
// partial layout: [b][chunk][c][8]
// ---------------------------------------------------------------------------
__global__ __launch_bounds__(256) void col_pass(
    const float* __restrict__ scores,
    const float* __restrict__ u, float* __restrict__ partial)
{
    const int tid = threadIdx.x;
    const int chunk = blockIdx.y;
    const int b = blockIdx.z;
    const int r0 = chunk * CHUNK;
    const int c0 = blockIdx.x * 512 + tid * 2;

    const float* __restrict__ ub = u + (size_t)b * UVS + r0;
    const float2* base2 = (const float2*)(scores + (size_t)b * M * N + (size_t)r0 * N) + (c0 >> 1);

    float tA[5], sA, tB[5], sB;
    #pragma unroll
    for (int g = 0; g < 8; ++g) {
        float2 q[8];
        #pragma unroll
        for (int k = 0; k < 8; ++k) q[k] = base2[(size_t)(8 * g + k) * (N / 2)];
        float zA[8], zB[8];
        #pragma unroll
        for (int k = 0; k < 8; ++k) {
            float uu = ub[8 * g + k];
            zA[k] = fmaf(q[k].x, LOG2E, uu);
            zB[k] = fmaf(q[k].y, LOG2E, uu);
        }
        group_accum(g == 0, tA, sA, zA);
        group_accum(g == 0, tB, sB, zB);
    }

    float4* pq = (float4*)(partial + (((size_t)(b * NCHUNK + chunk) * MP1) + c0) * 8);
    pq[0] = make_float4(tA[0], tA[1], tA[2], tA[3]);
    pq[1] = make_float4(tA[4], sA, 0.0f, 0.0f);
    pq[2] = make_float4(tB[0], tB[1], tB[2], tB[3]);
    pq[3] = make_float4(tB[4], sB, 0.0f, 0.0f);
}

// ---------------------------------------------------------------------------
// Col combine + fused MLP: grid (257, B), block 256 = 4 waves, TWO cols per
// wave. lane<NCHUNK loads both columns' partials; dual butterfly; dustbin row
// add; dual MLP. Dustbin column (c==N) wave reduces alpha2+u[] itself.
// ---------------------------------------------------------------------------
__global__ __launch_bounds__(256) void col_mlp_fused(
    const float* __restrict__ partial, const float* __restrict__ dB,
    const float* __restrict__ u, const float* __restrict__ alpha,
    float* __restrict__ v,
    const float* __restrict__ w1, const float* __restrict__ b1,
    const float* __restrict__ g1, const float* __restrict__ be1,
    const float* __restrict__ w2, const float* __restrict__ b2,
    const float* __restrict__ g2, const float* __restrict__ be2,
    const float* __restrict__ w3, const float* __restrict__ b3)
{
    const int tid  = threadIdx.x;
    const int lane = tid & 63;
    const int wv   = tid >> 6;
    const int pair = blockIdx.x * 4 + wv;
    const int c0   = pair * 2;
    if (c0 >= MP1) return;
    const int b = blockIdx.y;
    const float alpha2 = alpha[0] * LOG2E;
    const float uM = u[(size_t)b * UVS + M];

    if (c0 < N) {
        // ---- dual path: columns c0, c0+1 ----
        float tA[5], sA, tB[5], sB;
        if (lane < NCHUNK) {
            const float4* pq = (const float4*)(partial + (((size_t)(b * NCHUNK + lane) * MP1) + c0) * 8);
            float4 a0 = pq[0], a1 = pq[1], b0 = pq[2], b1v = pq[3];
            tA[0]=a0.x; tA[1]=a0.y; tA[2]=a0.z; tA[3]=a0.w; tA[4]=a1.x; sA=a1.y;
            tB[0]=b0.x; tB[1]=b0.y; tB[2]=b0.z; tB[3]=b0.w; tB[4]=b1v.x; sB=b1v.y;
        } else {
            #pragma unroll
            for (int k = 0; k < 5; ++k) { tA[k] = -INFINITY; tB[k] = -INFINITY; }
            sA = 0.0f; sB = 0.0f;
        }
        #pragma unroll
        for (int off = 32; off >= 1; off >>= 1) merge5_shfl_xor2(tA, sA, tB, sB, off);

        float extra = alpha2 + uM;   // dustbin row element, same for all columns
        online_add(tA, sA, extra);
        online_add(tB, sB, extra);

        float fA[16], fB[16], vnA, vnB;
        const float* ddA = dB + (size_t)(b * MP1 + c0) * 8;
        const float* ddB = ddA + 8;
        feats_from(tA, sA, -12.0f, 0.0f, ddA, fA, vnA);
        feats_from(tB, sB, -12.0f, 0.0f, ddB, fB, vnB);

        float oA, oB;
        mlp_wave2(fA, fB, lane, w1, b1, g1, be1, w2, b2, g2, be2, w3, b3, oA, oB);
        if (lane == 0) {
            v[(size_t)b * UVS + c0]     = vnA + oA * LOG2E;
            v[(size_t)b * UVS + c0 + 1] = vnB + oB * LOG2E;
        }
    } else {
        // ---- dustbin column c == N: reduce alpha2 + u[r] over r=0..M ----
        const float4* u4 = (const float4*)(u + (size_t)b * UVS);
        float4 qq[8];
        #pragma unroll
        for (int j = 0; j < 8; ++j) qq[j] = u4[lane + 64 * j];
        float t[5], s;
        #pragma unroll
        for (int g = 0; g < 4; ++g) {
            float4 qa = qq[2 * g], qb = qq[2 * g + 1];
            float z[8];
            z[0]=alpha2+qa.x; z[1]=alpha2+qa.y; z[2]=alpha2+qa.z; z[3]=alpha2+qa.w;
            z[4]=alpha2+qb.x; z[5]=alpha2+qb.y; z[6]=alpha2+qb.z; z[7]=alpha2+qb.w;
            group_accum(g == 0, t, s, z);
        }
        #pragma unroll
        for (int off = 32; off >= 1; off >>= 1) merge5_shfl_xor(t, s, off);
        online_add(t, s, alpha2 + uM);   // corner element S[M,N]

        float f[16], vn;
        const float* dd = dB + (size_t)(b * MP1 + N) * 8;
        feats_from(t, s, -1.0f, 0.0f, dd, f, vn);
        float o = mlp_wave(f, lane, w1, b1, g1, be1, w2, b2, g2, be2, w3, b3);
        if (lane == 0) v[(size_t)b * UVS + N] = vn + o * LOG2E;
    }
}

// ---------------------------------------------------------------------------
// out[b,r,c] = S*LOG2E + u[b,r] + v[b,c] + 12.  grid (2049, B), block 256.
// float4 loads; scalar stores (out rows are 2049 floats -> unaligned).
// ---------------------------------------------------------------------------
__global__ __launch_bounds__(256) void final_kernel(
    const float* __restrict__ scores, const float* __restrict__ alpha,
    const float* __restrict__ u, const float* __restrict__ v,
    float* __restrict__ out)
{
    const int r = blockIdx.x;
    const int b = blockIdx.y;
    const int tid = threadIdx.x;
    const float alpha2 = alpha[0] * LOG2E;
    const float* vb = v + (size_t)b * UVS;
    const float4* v4 = (const float4*)vb;
    const float ur = u[(size_t)b * UVS + r] + 12.0f;
    float* orow = out + ((size_t)b * MP1 + r) * MP1;

    if (r < M) {
        const float4* s4 = (const float4*)(scores + ((size_t)b * M + r) * N);
        #pragma unroll
        for (int k = 0; k < 2; ++k) {
            int j = tid + 256 * k;           // float4 index, c = 4j
            float4 sv = s4[j];
            float4 vv = v4[j];
            int c = 4 * j;
            orow[c]     = fmaf(sv.x, LOG2E, ur + vv.x);
            orow[c + 1] = fmaf(sv.y, LOG2E, ur + vv.y);
            orow[c + 2] = fmaf(sv.z, LOG2E, ur + vv.z);
            orow[c + 3] = fmaf(sv.w, LOG2E, ur + vv.w);
        }
    } else {
        #pragma unroll
        for (int k = 0; k < 2; ++k) {
            int j = tid + 256 * k;
            float4 vv = v4[j];
            int c = 4 * j;
            orow[c]     = alpha2 + ur + vv.x;
            orow[c + 1] = alpha2 + ur + vv.y;
            orow[c + 2] = alpha2 + ur + vv.z;
            orow[c + 3] = alpha2 + ur + vv.w;
        }
    }
    if (tid == 0) orow[N] = alpha2 + ur + vb[N];
}

extern "C" void kernel_launch(void* const* d_in, const int* in_sizes, int n_in,
                              void* d_out, int out_size, void* d_ws, size_t ws_size,
                              hipStream_t stream) {
    const float* scores = (const float*)d_in[0];
    const float* alpha  = (const float*)d_in[1];
    const float* mdesc0 = (const float*)d_in[2];
    const float* mdesc1 = (const float*)d_in[3];
    const float* pA_w = (const float*)d_in[4];
    const float* pA_b = (const float*)d_in[5];
    const float* pB_w = (const float*)d_in[6];
    const float* pB_b = (const float*)d_in[7];
    const float* rW[10]; const float* cW[10];
    for (int k = 0; k < 10; ++k) rW[k] = (const float*)d_in[8 + k];
    for (int k = 0; k < 10; ++k) cW[k] = (const float*)d_in[18 + k];
    float* out = (float*)d_out;

    const int B = in_sizes[0] / (M * N);

    float* ws = (float*)d_ws;
    float* u       = ws;                        // B*UVS
    float* v       = u + (size_t)B * UVS;       // B*UVS
    float* dA      = v + (size_t)B * UVS;       // B*MP1*8
    float* dB      = dA + (size_t)B * MP1 * 8;  // B*MP1*8
    float* partial = dB + (size_t)B * MP1 * 8;  // B*NCHUNK*MP1*8

    const int CB = (MP1 + 255) / 256;           // 9
    const int PB = ((MP1 + 1) / 2 + 3) / 4;     // 257: 2 rows/cols per wave, 4 waves/block

    proj_kernel<<<dim3(CB, B, 2), 256, 0, stream>>>(
        mdesc0, mdesc1, pA_w, pA_b, pB_w, pB_b, dA, dB);

    for (int it = 0; it < 3; ++it) {
        row_fused<<<dim3(PB, B), 256, 0, stream>>>(
            scores, alpha, v, dA, u, it == 0 ? 1 : 0,
            rW[0], rW[1], rW[2], rW[3], rW[4], rW[5], rW[6], rW[7], rW[8], rW[9]);
        col_pass<<<dim3(4, NCHUNK, B), 256, 0, stream>>>(scores, u, partial);
        col_mlp_fused<<<dim3(PB, B), 256, 0, stream>>>(
            partial, dB, u, alpha, v,
            cW[0], cW[1], cW[2], cW[3], cW[4], cW[5], cW[6], cW[7], cW[8], cW[9]);
    }
    final_kernel<<<dim3(MP1, B), 256, 0, stream>>>(scores, alpha, u, v, out);
}